// Round 19
// baseline (475.783 us; speedup 1.0000x reference)
//
#include <hip/hip_runtime.h>
#include <hip/hip_bf16.h>

#define T_LEN 32768
#define B_N   4
#define RC    32
#define DC    32
#define SC    256
#define OUTC  256
#define NL    40
#define KTOT  (NL * RC)   // 1280
#define NBT   (B_N * T_LEN)
#define SLOTB ((size_t)NBT * 32 * 2)   // 8 MB per stream slot
#define BTW   128                       // bt per k_skipfinal block
#define RING  24576                     // ring slot: A 16 KB + B 8 KB

typedef float f32x4 __attribute__((ext_vector_type(4)));
typedef short bf16x8 __attribute__((ext_vector_type(8)));
typedef __attribute__((address_space(3))) unsigned int lds_u32;
typedef __attribute__((address_space(3))) char lds_char;
typedef __attribute__((address_space(1))) unsigned int glb_u32;

// ---------- helpers ----------
__device__ __forceinline__ unsigned short f2bf_bits(float f) {
    __hip_bfloat16 b = __float2bfloat16(f);
    unsigned short u;
    __builtin_memcpy(&u, &b, 2);
    return u;
}
__device__ __forceinline__ unsigned pack2(float a, float b) {
    return (unsigned)f2bf_bits(a) | ((unsigned)f2bf_bits(b) << 16);
}
__device__ __forceinline__ float bflo(unsigned u) { return __uint_as_float((u & 0xFFFFu) << 16); }
__device__ __forceinline__ float bfhi(unsigned u) { return __uint_as_float(u & 0xFFFF0000u); }
__device__ __forceinline__ float ftanh(float x) {
    float e = __expf(2.f * x);
    return 1.f - 2.f / (e + 1.f);
}
// swizzle involution: XOR col bits 4-5 with (row>>1)&3  (row = byte>>6)
__device__ __forceinline__ int swz(int L) { return L ^ ((((L >> 7) & 3)) << 4); }
__device__ __forceinline__ void wait_vmcnt(int n) {
    switch (n) {
        case 0: asm volatile("s_waitcnt vmcnt(0)" ::: "memory"); break;
        case 6: asm volatile("s_waitcnt vmcnt(6)" ::: "memory"); break;
        default: asm volatile("s_waitcnt vmcnt(12)" ::: "memory"); break;
    }
}

// ---------- prep: bf16 weight packs + bias sum ----------
__global__ __launch_bounds__(256) void k_prep(const float* __restrict__ Ws,
                                              const float* __restrict__ Wf,
                                              const float* __restrict__ Wd,
                                              const float* __restrict__ Wr,
                                              const float* __restrict__ bs,
                                              unsigned short* __restrict__ Wsk2,
                                              unsigned short* __restrict__ Wfk,
                                              unsigned short* __restrict__ Wd1k,
                                              unsigned short* __restrict__ Wd0k,
                                              unsigned short* __restrict__ Wrk,
                                              float* __restrict__ bs_sum) {
    int g = blockIdx.x * 256 + threadIdx.x;
    if (g < SC * KTOT) {
        int i = g >> 13, r = g & 8191;
        int oc = r >> 5, c = r & 31;
        Wsk2[g] = f2bf_bits(Ws[(i * SC + oc) * RC + c]);
        return;
    }
    g -= SC * KTOT;
    if (g < OUTC * SC) { Wfk[g] = f2bf_bits(Wf[g]); return; }
    g -= OUTC * SC;
    if (g < NL * 1024) {
        int i = g >> 10, r = g & 1023;
        int o = r >> 5, c = r & 31;
        Wd1k[g] = f2bf_bits(Wd[((i * DC + o) * RC + c) * 2 + 1]);
        return;
    }
    g -= NL * 1024;
    if (g < NL * 1024) {
        int i = g >> 10, r = g & 1023;
        int o = r >> 5, c = r & 31;
        Wd0k[g] = f2bf_bits(Wd[((i * DC + o) * RC + c) * 2 + 0]);
        return;
    }
    g -= NL * 1024;
    if (g < NL * 1024) { Wrk[g] = f2bf_bits(Wr[g]); return; }
    g -= NL * 1024;
    if (g < SC) {
        float s = 0.f;
        for (int i = 0; i < NL; ++i) s += bs[i * SC + g];
        bs_sum[g] = s;
    }
}

// ---------- start conv -> bf16 stream slot 0 ----------
__global__ __launch_bounds__(256) void k_start(const float* __restrict__ x,
                                               const float* __restrict__ Wst,
                                               const float* __restrict__ bst,
                                               unsigned short* __restrict__ h0) {
    int g = blockIdx.x * 256 + threadIdx.x;
    float xv = x[g];
    unsigned u[16];
#pragma unroll
    for (int q = 0; q < 16; ++q) {
        float a = Wst[2 * q] * xv + bst[2 * q];
        float b = Wst[2 * q + 1] * xv + bst[2 * q + 1];
        u[q] = pack2(a, b);
    }
    unsigned short* op = h0 + (size_t)g * 32;
#pragma unroll
    for (int q = 0; q < 4; ++q) *(uint4*)&op[q * 8] = *(uint4*)&u[q * 4];
}

// ---------- one WaveNet layer: 16 bt/wave, high occupancy (target <=64 VGPR) ----------
// Same per-element math as the proven 32-bt k_layer (n-loop collapsed) -> bit-identical.
__global__ __launch_bounds__(256, 8) void k_layer_sm(const unsigned short* __restrict__ hprev,
                                                     unsigned short* __restrict__ hnext,
                                                     const unsigned short* __restrict__ Wd1k,
                                                     const unsigned short* __restrict__ Wd0k,
                                                     const unsigned short* __restrict__ Wrk,
                                                     const float* __restrict__ bd,
                                                     const float* __restrict__ br,
                                                     int d) {
    __shared__ unsigned short zbuf[4][16 * 40];
    const int lane = threadIdx.x & 63;
    const int wq = threadIdx.x >> 6;
    const int lr = lane & 15, lg = lane >> 4;
    const int bt = blockIdx.x * 64 + wq * 16 + lr;
    const int t = bt & (T_LEN - 1);
    unsigned short* zp = &zbuf[wq][0];

    // input frags
    const unsigned short* hp = hprev + (size_t)bt * 32;
    bf16x8 hc = *(const bf16x8*)(hp + 8 * lg);
    bf16x8 hs;
    {
        int bts = (t >= d) ? (bt - d) : bt;
        bf16x8 v = *(const bf16x8*)(hprev + (size_t)bts * 32 + 8 * lg);
        if (t < d) v = (bf16x8){0, 0, 0, 0, 0, 0, 0, 0};
        hs = v;
    }
    uint2 hcc0 = *(const uint2*)(hp + 4 * lg);
    uint2 hcc1 = *(const uint2*)(hp + 16 + 4 * lg);

    // conv MFMAs (weights loaded in-place, short live ranges)
    f32x4 z0, z1;
    {
        bf16x8 w00 = *(const bf16x8*)(Wd0k + lr * 32 + 8 * lg);
        bf16x8 w01 = *(const bf16x8*)(Wd0k + (16 + lr) * 32 + 8 * lg);
        bf16x8 w10 = *(const bf16x8*)(Wd1k + lr * 32 + 8 * lg);
        bf16x8 w11 = *(const bf16x8*)(Wd1k + (16 + lr) * 32 + 8 * lg);
        z0 = __builtin_amdgcn_mfma_f32_16x16x32_bf16(w00, hs, (f32x4){0.f, 0.f, 0.f, 0.f}, 0, 0, 0);
        z0 = __builtin_amdgcn_mfma_f32_16x16x32_bf16(w10, hc, z0, 0, 0, 0);
        z1 = __builtin_amdgcn_mfma_f32_16x16x32_bf16(w01, hs, (f32x4){0.f, 0.f, 0.f, 0.f}, 0, 0, 0);
        z1 = __builtin_amdgcn_mfma_f32_16x16x32_bf16(w11, hc, z1, 0, 0, 0);
    }

    // tanh + pack -> per-wave LDS (C layout)
    {
        float4 b0 = *(const float4*)(bd + 4 * lg);
        uint2 u;
        u.x = pack2(ftanh(z0[0] + b0.x), ftanh(z0[1] + b0.y));
        u.y = pack2(ftanh(z0[2] + b0.z), ftanh(z0[3] + b0.w));
        *(uint2*)(zp + lr * 40 + 4 * lg) = u;
        float4 b1 = *(const float4*)(bd + 16 + 4 * lg);
        u.x = pack2(ftanh(z1[0] + b1.x), ftanh(z1[1] + b1.y));
        u.y = pack2(ftanh(z1[2] + b1.z), ftanh(z1[3] + b1.w));
        *(uint2*)(zp + lr * 40 + 16 + 4 * lg) = u;
    }

    // residual MFMAs
    f32x4 r0, r1;
    {
        bf16x8 zb = *(const bf16x8*)(zp + lr * 40 + 8 * lg);
        bf16x8 wr0 = *(const bf16x8*)(Wrk + lr * 32 + 8 * lg);
        bf16x8 wr1 = *(const bf16x8*)(Wrk + (16 + lr) * 32 + 8 * lg);
        r0 = __builtin_amdgcn_mfma_f32_16x16x32_bf16(wr0, zb, (f32x4){0.f, 0.f, 0.f, 0.f}, 0, 0, 0);
        r1 = __builtin_amdgcn_mfma_f32_16x16x32_bf16(wr1, zb, (f32x4){0.f, 0.f, 0.f, 0.f}, 0, 0, 0);
    }

    // h' = hc + r + br ; bf16 store
    unsigned short* op = hnext + (size_t)bt * 32;
    {
        float4 brv = *(const float4*)(br + 4 * lg);
        uint2 u;
        u.x = pack2(bflo(hcc0.x) + r0[0] + brv.x, bfhi(hcc0.x) + r0[1] + brv.y);
        u.y = pack2(bflo(hcc0.y) + r0[2] + brv.z, bfhi(hcc0.y) + r0[3] + brv.w);
        *(uint2*)(op + 4 * lg) = u;
    }
    {
        float4 brv = *(const float4*)(br + 16 + 4 * lg);
        uint2 u;
        u.x = pack2(bflo(hcc1.x) + r1[0] + brv.x, bfhi(hcc1.x) + r1[1] + brv.y);
        u.y = pack2(bflo(hcc1.y) + r1[2] + brv.z, bfhi(hcc1.y) + r1[3] + brv.w);
        *(uint2*)(op + 16 + 4 * lg) = u;
    }
}

// ---------- fused skip + final GEMM (R16 verbatim: 124 us measured) ----------
__global__ __launch_bounds__(256, 2) void k_skipfinal(const unsigned short* __restrict__ hist,
                                                      const unsigned short* __restrict__ Wsk2,
                                                      const unsigned short* __restrict__ Wfk,
                                                      const float* __restrict__ bs_sum,
                                                      const float* __restrict__ bfv,
                                                      float* __restrict__ outp) {
    __shared__ char smem[73728];
    const int tid = threadIdx.x;
    const int lane = tid & 63, wq = tid >> 6;
    const int lr = lane & 15, lg = lane >> 4;
    const int wm = wq & 1, wn = wq >> 1;
    const int bt0 = blockIdx.x * BTW;
    const char* histb = (const char*)hist;
    const char* Wsb = (const char*)Wsk2;
    lds_char* smem3 = (lds_char*)smem;

    int asrc[4], bsrc[2];
#pragma unroll
    for (int p = 0; p < 4; ++p) asrc[p] = swz(p * 4096 + tid * 16);
#pragma unroll
    for (int p = 0; p < 2; ++p) bsrc[p] = bt0 * 64 + swz(p * 4096 + tid * 16);

    auto stage = [&](int k) {
        int sl = NL - 1 - k;
        char* base = smem + (k % 3) * RING;
#pragma unroll
        for (int p = 0; p < 4; ++p)
            __builtin_amdgcn_global_load_lds((const glb_u32*)(Wsb + (size_t)sl * 16384 + asrc[p]),
                                             (lds_u32*)(base + p * 4096 + tid * 16), 16, 0, 0);
#pragma unroll
        for (int p = 0; p < 2; ++p)
            __builtin_amdgcn_global_load_lds((const glb_u32*)(histb + (size_t)sl * SLOTB + bsrc[p]),
                                             (lds_u32*)(base + 16384 + p * 4096 + tid * 16), 16, 0, 0);
    };

    f32x4 acc[8][4];
#pragma unroll
    for (int m = 0; m < 8; ++m)
#pragma unroll
        for (int n = 0; n < 4; ++n) acc[m][n] = (f32x4){0.f, 0.f, 0.f, 0.f};

    const int cswz = (lg * 16) ^ (((lr >> 1) & 3) << 4);
    const int arow = wm * 128 + lr;
    const int brow = wn * 64 + lr;

    stage(0);
    stage(1);
    stage(2);

#pragma unroll
    for (int i = 0; i < NL; ++i) {
        if (i >= 1 && i + 2 < NL) stage(i + 2);
        wait_vmcnt(i + 2 < NL ? 12 : (i + 1 < NL ? 6 : 0));
        __builtin_amdgcn_s_barrier();

        lds_char* Ab = smem3 + (i % 3) * RING;
        lds_char* Bb = Ab + 16384;
        bf16x8 af[8], bb[4];
#pragma unroll
        for (int m = 0; m < 8; ++m)
            asm volatile("ds_read_b128 %0, %1" : "=v"(af[m]) : "v"(Ab + (arow + m * 16) * 64 + cswz));
#pragma unroll
        for (int n = 0; n < 4; ++n)
            asm volatile("ds_read_b128 %0, %1" : "=v"(bb[n]) : "v"(Bb + (brow + n * 16) * 64 + cswz));
        asm volatile("s_waitcnt lgkmcnt(0)" ::: "memory");
        __builtin_amdgcn_sched_barrier(0);

#pragma unroll
        for (int m = 0; m < 8; ++m)
#pragma unroll
            for (int n = 0; n < 4; ++n)
                acc[m][n] = __builtin_amdgcn_mfma_f32_16x16x32_bf16(af[m], bb[n], acc[m][n], 0, 0, 0);
        __builtin_amdgcn_s_barrier();
    }
    __syncthreads();

    char* skb = smem;
#pragma unroll
    for (int m = 0; m < 8; ++m) {
        int oc0 = wm * 128 + m * 16 + lg * 4;
        float c0 = bs_sum[oc0], c1 = bs_sum[oc0 + 1], c2 = bs_sum[oc0 + 2], c3 = bs_sum[oc0 + 3];
#pragma unroll
        for (int n = 0; n < 4; ++n) {
            int bt = wn * 64 + n * 16 + lr;
            f32x4 v = acc[m][n];
            uint2 u;
            u.x = pack2(fmaxf(v[0] + c0, 0.f), fmaxf(v[1] + c1, 0.f));
            u.y = pack2(fmaxf(v[2] + c2, 0.f), fmaxf(v[3] + c3, 0.f));
            int L = bt * 512 + oc0 * 2;
            *(uint2*)(skb + (L ^ ((bt & 7) << 4))) = u;
        }
    }
    __syncthreads();

#pragma unroll
    for (int m = 0; m < 8; ++m)
#pragma unroll
        for (int n = 0; n < 4; ++n) acc[m][n] = (f32x4){0.f, 0.f, 0.f, 0.f};

    const unsigned short* Fb = Wfk + (size_t)(wm * 128 + lr) * SC + 8 * lg;

#pragma unroll
    for (int kk = 0; kk < SC / 32; ++kk) {
        bf16x8 fa[8];
#pragma unroll
        for (int m = 0; m < 8; ++m) fa[m] = *(const bf16x8*)(Fb + (size_t)m * 16 * SC + kk * 32);
        bf16x8 sbv[4];
#pragma unroll
        for (int n = 0; n < 4; ++n) {
            int bt = wn * 64 + n * 16 + lr;
            int L = bt * 512 + kk * 64 + lg * 16;
            sbv[n] = *(const bf16x8*)(skb + (L ^ ((bt & 7) << 4)));
        }
#pragma unroll
        for (int m = 0; m < 8; ++m)
#pragma unroll
            for (int n = 0; n < 4; ++n)
                acc[m][n] = __builtin_amdgcn_mfma_f32_16x16x32_bf16(fa[m], sbv[n], acc[m][n], 0, 0, 0);
    }

    int b2 = bt0 >> 15;
    int t0 = bt0 & (T_LEN - 1);
#pragma unroll
    for (int m = 0; m < 8; ++m) {
        int o0 = wm * 128 + m * 16 + lg * 4;
        float q0 = bfv[o0], q1 = bfv[o0 + 1], q2 = bfv[o0 + 2], q3 = bfv[o0 + 3];
#pragma unroll
        for (int n = 0; n < 4; ++n) {
            int t = t0 + wn * 64 + n * 16 + lr;
            f32x4 v = acc[m][n];
            outp[((size_t)(b2 * OUTC + o0 + 0) << 15) + t] = v[0] + q0;
            outp[((size_t)(b2 * OUTC + o0 + 1) << 15) + t] = v[1] + q1;
            outp[((size_t)(b2 * OUTC + o0 + 2) << 15) + t] = v[2] + q2;
            outp[((size_t)(b2 * OUTC + o0 + 3) << 15) + t] = v[3] + q3;
        }
    }
}

extern "C" void kernel_launch(void* const* d_in, const int* in_sizes, int n_in,
                              void* d_out, int out_size, void* d_ws, size_t ws_size,
                              hipStream_t stream) {
    const float* x       = (const float*)d_in[0];
    const float* W_start = (const float*)d_in[1];
    const float* b_start = (const float*)d_in[2];
    const float* Wd      = (const float*)d_in[3];
    const float* bd      = (const float*)d_in[4];
    const float* Wr      = (const float*)d_in[5];
    const float* br      = (const float*)d_in[6];
    const float* Ws      = (const float*)d_in[7];
    const float* bs      = (const float*)d_in[8];
    const float* Wf      = (const float*)d_in[9];
    const float* bfv     = (const float*)d_in[10];

    char* wsb = (char*)d_ws;
    unsigned short* Wsk2 = (unsigned short*)(wsb);                      // 655360 B
    unsigned short* Wfk  = (unsigned short*)(wsb + 655360);             // 131072 B
    unsigned short* Wd1k = (unsigned short*)(wsb + 786432);             // 81920 B
    unsigned short* Wd0k = (unsigned short*)(wsb + 868352);             // 81920 B
    unsigned short* Wrk  = (unsigned short*)(wsb + 950272);             // 81920 B
    float*          bs_sum = (float*)(wsb + 1032192);                   // 1024 B
    char* S1 = wsb + (1 << 20);            // stream slots 1..40 (= hist layers 0..39)
    char* X  = S1 + 40 * SLOTB;            // slot 0

    auto slotptr = [&](int i) -> unsigned short* {
        return (unsigned short*)(i == 0 ? X : S1 + (size_t)(i - 1) * SLOTB);
    };

    k_prep<<<(SC * KTOT + OUTC * SC + 3 * NL * 1024 + SC + 255) / 256, 256, 0, stream>>>(
        Ws, Wf, Wd, Wr, bs, Wsk2, Wfk, Wd1k, Wd0k, Wrk, bs_sum);
    k_start<<<NBT / 256, 256, 0, stream>>>(x, W_start, b_start, slotptr(0));

    for (int i = 0; i < NL; ++i) {
        int d = 1 << (i % 10);
        k_layer_sm<<<NBT / 64, 256, 0, stream>>>(slotptr(i), slotptr(i + 1),
                                                 Wd1k + i * 1024, Wd0k + i * 1024, Wrk + i * 1024,
                                                 bd + i * DC, br + i * RC, d);
    }

    k_skipfinal<<<NBT / BTW, 256, 0, stream>>>((unsigned short*)S1, Wsk2, Wfk, bs_sum, bfv, (float*)d_out);
}

// Round 20
// 418.731 us; speedup vs baseline: 1.1363x; 1.1363x over previous
//
#include <hip/hip_runtime.h>
#include <hip/hip_bf16.h>

#define T_LEN 32768
#define B_N   4
#define RC    32
#define DC    32
#define SC    256
#define OUTC  256
#define NL    40
#define KTOT  (NL * RC)   // 1280
#define NBT   (B_N * T_LEN)
#define SLOTB ((size_t)NBT * 32 * 2)   // 8 MB per stream slot
#define BTW   128                       // bt per k_skipfinal block
#define RING  24576                     // ring slot: A 16 KB + B 8 KB
#define H2    128                       // k_layer2 halo

typedef float f32x4 __attribute__((ext_vector_type(4)));
typedef short bf16x8 __attribute__((ext_vector_type(8)));
typedef __attribute__((address_space(3))) unsigned int lds_u32;
typedef __attribute__((address_space(3))) char lds_char;
typedef __attribute__((address_space(1))) unsigned int glb_u32;

// ---------- helpers ----------
__device__ __forceinline__ unsigned short f2bf_bits(float f) {
    __hip_bfloat16 b = __float2bfloat16(f);
    unsigned short u;
    __builtin_memcpy(&u, &b, 2);
    return u;
}
__device__ __forceinline__ unsigned pack2(float a, float b) {
    return (unsigned)f2bf_bits(a) | ((unsigned)f2bf_bits(b) << 16);
}
__device__ __forceinline__ float bflo(unsigned u) { return __uint_as_float((u & 0xFFFFu) << 16); }
__device__ __forceinline__ float bfhi(unsigned u) { return __uint_as_float(u & 0xFFFF0000u); }
__device__ __forceinline__ float ftanh(float x) {
    float e = __expf(2.f * x);
    return 1.f - 2.f / (e + 1.f);
}
// swizzle involution: XOR col bits 4-5 with (row>>1)&3  (row = byte>>6)
__device__ __forceinline__ int swz(int L) { return L ^ ((((L >> 7) & 3)) << 4); }
// mid-buffer byte address: row u (64 B), col byte c, same involution
__device__ __forceinline__ int midaddr(int u, int c) { return u * 64 + (c ^ (((u >> 1) & 3) << 4)); }
__device__ __forceinline__ void wait_vmcnt(int n) {
    switch (n) {
        case 0: asm volatile("s_waitcnt vmcnt(0)" ::: "memory"); break;
        case 6: asm volatile("s_waitcnt vmcnt(6)" ::: "memory"); break;
        default: asm volatile("s_waitcnt vmcnt(12)" ::: "memory"); break;
    }
}

// ---------- prep: bf16 weight packs + bias sum ----------
__global__ __launch_bounds__(256) void k_prep(const float* __restrict__ Ws,
                                              const float* __restrict__ Wf,
                                              const float* __restrict__ Wd,
                                              const float* __restrict__ Wr,
                                              const float* __restrict__ bs,
                                              unsigned short* __restrict__ Wsk2,
                                              unsigned short* __restrict__ Wfk,
                                              unsigned short* __restrict__ Wd1k,
                                              unsigned short* __restrict__ Wd0k,
                                              unsigned short* __restrict__ Wrk,
                                              float* __restrict__ bs_sum) {
    int g = blockIdx.x * 256 + threadIdx.x;
    if (g < SC * KTOT) {
        int i = g >> 13, r = g & 8191;
        int oc = r >> 5, c = r & 31;
        Wsk2[g] = f2bf_bits(Ws[(i * SC + oc) * RC + c]);
        return;
    }
    g -= SC * KTOT;
    if (g < OUTC * SC) { Wfk[g] = f2bf_bits(Wf[g]); return; }
    g -= OUTC * SC;
    if (g < NL * 1024) {
        int i = g >> 10, r = g & 1023;
        int o = r >> 5, c = r & 31;
        Wd1k[g] = f2bf_bits(Wd[((i * DC + o) * RC + c) * 2 + 1]);
        return;
    }
    g -= NL * 1024;
    if (g < NL * 1024) {
        int i = g >> 10, r = g & 1023;
        int o = r >> 5, c = r & 31;
        Wd0k[g] = f2bf_bits(Wd[((i * DC + o) * RC + c) * 2 + 0]);
        return;
    }
    g -= NL * 1024;
    if (g < NL * 1024) { Wrk[g] = f2bf_bits(Wr[g]); return; }
    g -= NL * 1024;
    if (g < SC) {
        float s = 0.f;
        for (int i = 0; i < NL; ++i) s += bs[i * SC + g];
        bs_sum[g] = s;
    }
}

// ---------- start conv -> bf16 stream slot 0 ----------
__global__ __launch_bounds__(256) void k_start(const float* __restrict__ x,
                                               const float* __restrict__ Wst,
                                               const float* __restrict__ bst,
                                               unsigned short* __restrict__ h0) {
    int g = blockIdx.x * 256 + threadIdx.x;
    float xv = x[g];
    unsigned u[16];
#pragma unroll
    for (int q = 0; q < 16; ++q) {
        float a = Wst[2 * q] * xv + bst[2 * q];
        float b = Wst[2 * q + 1] * xv + bst[2 * q + 1];
        u[q] = pack2(a, b);
    }
    unsigned short* op = h0 + (size_t)g * 32;
#pragma unroll
    for (int q = 0; q < 4; ++q) *(uint4*)&op[q * 8] = *(uint4*)&u[q * 4];
}

// ---------- one WaveNet layer: MFMA, bf16 stream (R8 body; occupancy hint 6 waves/EU) ----------
__global__ __launch_bounds__(256, 6) void k_layer(const unsigned short* __restrict__ hprev,
                                                  unsigned short* __restrict__ hnext,
                                                  const unsigned short* __restrict__ Wd1k,
                                                  const unsigned short* __restrict__ Wd0k,
                                                  const unsigned short* __restrict__ Wrk,
                                                  const float* __restrict__ bd,
                                                  const float* __restrict__ br,
                                                  int d) {
    __shared__ unsigned short zbuf[4][32 * 40];
    int lane = threadIdx.x & 63;
    int wq = threadIdx.x >> 6;
    int lr = lane & 15, lg = lane >> 4;
    int btb = blockIdx.x * 128 + wq * 32;
    unsigned short* zp = &zbuf[wq][0];

    bf16x8 wd1[2], wd0[2], wr[2];
#pragma unroll
    for (int m = 0; m < 2; ++m) {
        int ao = (m * 16 + lr) * 32 + 8 * lg;
        wd1[m] = *(const bf16x8*)(Wd1k + ao);
        wd0[m] = *(const bf16x8*)(Wd0k + ao);
        wr[m]  = *(const bf16x8*)(Wrk + ao);
    }

    bf16x8 hc[2], hs[2];
    uint2 hcc[2][2];
#pragma unroll
    for (int n = 0; n < 2; ++n) {
        int bt = btb + n * 16 + lr;
        int t = bt & (T_LEN - 1);
        const unsigned short* hp = hprev + (size_t)bt * 32;
        hc[n] = *(const bf16x8*)(hp + 8 * lg);
        int bts = (t >= d) ? (bt - d) : bt;
        bf16x8 v = *(const bf16x8*)(hprev + (size_t)bts * 32 + 8 * lg);
        if (t < d) v = (bf16x8){0, 0, 0, 0, 0, 0, 0, 0};
        hs[n] = v;
#pragma unroll
        for (int m = 0; m < 2; ++m) hcc[n][m] = *(const uint2*)(hp + m * 16 + 4 * lg);
    }

    f32x4 zac[2][2];
#pragma unroll
    for (int m = 0; m < 2; ++m)
#pragma unroll
        for (int n = 0; n < 2; ++n) {
            f32x4 a = __builtin_amdgcn_mfma_f32_16x16x32_bf16(wd0[m], hs[n], (f32x4){0.f, 0.f, 0.f, 0.f}, 0, 0, 0);
            zac[m][n] = __builtin_amdgcn_mfma_f32_16x16x32_bf16(wd1[m], hc[n], a, 0, 0, 0);
        }

#pragma unroll
    for (int m = 0; m < 2; ++m) {
        float4 bdv = *(const float4*)(bd + m * 16 + 4 * lg);
#pragma unroll
        for (int n = 0; n < 2; ++n) {
            int rbt = n * 16 + lr;
            float z0 = ftanh(zac[m][n][0] + bdv.x);
            float z1 = ftanh(zac[m][n][1] + bdv.y);
            float z2 = ftanh(zac[m][n][2] + bdv.z);
            float z3 = ftanh(zac[m][n][3] + bdv.w);
            uint2 u;
            u.x = pack2(z0, z1);
            u.y = pack2(z2, z3);
            *(uint2*)(zp + rbt * 40 + m * 16 + 4 * lg) = u;
        }
    }

    f32x4 racc[2][2];
#pragma unroll
    for (int n = 0; n < 2; ++n) {
        int rbt = n * 16 + lr;
        bf16x8 zb = *(const bf16x8*)(zp + rbt * 40 + 8 * lg);
#pragma unroll
        for (int m = 0; m < 2; ++m)
            racc[m][n] = __builtin_amdgcn_mfma_f32_16x16x32_bf16(wr[m], zb, (f32x4){0.f, 0.f, 0.f, 0.f}, 0, 0, 0);
    }

#pragma unroll
    for (int m = 0; m < 2; ++m) {
        float4 brv = *(const float4*)(br + m * 16 + 4 * lg);
#pragma unroll
        for (int n = 0; n < 2; ++n) {
            int bt = btb + n * 16 + lr;
            float h0 = bflo(hcc[n][m].x) + racc[m][n][0] + brv.x;
            float h1 = bfhi(hcc[n][m].x) + racc[m][n][1] + brv.y;
            float h2 = bflo(hcc[n][m].y) + racc[m][n][2] + brv.z;
            float h3 = bfhi(hcc[n][m].y) + racc[m][n][3] + brv.w;
            uint2 u;
            u.x = pack2(h0, h1);
            u.y = pack2(h2, h3);
            *(uint2*)(hnext + (size_t)bt * 32 + m * 16 + 4 * lg) = u;
        }
    }
}

// ---------- fused pair of layers (d2 = 2*d1 <= 128); occupancy hint 3 ----------
__global__ __launch_bounds__(512, 3) void k_layer2(const unsigned short* __restrict__ hin,
                                                   unsigned short* __restrict__ hmid,
                                                   unsigned short* __restrict__ hfin,
                                                   const unsigned short* __restrict__ W1a,
                                                   const unsigned short* __restrict__ W0a,
                                                   const unsigned short* __restrict__ Wra,
                                                   const float* __restrict__ bda,
                                                   const float* __restrict__ bra,
                                                   const unsigned short* __restrict__ W1b,
                                                   const unsigned short* __restrict__ W0b,
                                                   const unsigned short* __restrict__ Wrb,
                                                   const float* __restrict__ bdb,
                                                   const float* __restrict__ brb,
                                                   int d1, int d2) {
    __shared__ char midb[384 * 64];                 // 24 KB mid buffer
    __shared__ unsigned short zbuf[8][32 * 40];     // 20 KB
    const int tid = threadIdx.x;
    const int lane = tid & 63, wq = tid >> 6;
    const int lr = lane & 15, lg = lane >> 4;
    const int bt0 = blockIdx.x * 256;
    unsigned short* zp = &zbuf[wq][0];

    bf16x8 wd1[2], wd0[2], wr[2];
    float4 bdv[2], brv[2];
#pragma unroll
    for (int m = 0; m < 2; ++m) {
        int ao = (m * 16 + lr) * 32 + 8 * lg;
        wd1[m] = *(const bf16x8*)(W1a + ao);
        wd0[m] = *(const bf16x8*)(W0a + ao);
        wr[m]  = *(const bf16x8*)(Wra + ao);
        bdv[m] = *(const float4*)(bda + m * 16 + 4 * lg);
        brv[m] = *(const float4*)(bra + m * 16 + 4 * lg);
    }

#pragma unroll 1
    for (int pass = 0; pass < 2; ++pass) {
        int tl = (pass == 0) ? wq : (wq + 8);
        if (pass == 1 && wq >= 4) break;
        int btb = bt0 - H2 + tl * 32;

        bf16x8 hc[2], hs[2];
        uint2 hcc[2][2];
#pragma unroll
        for (int n = 0; n < 2; ++n) {
            int bt = btb + n * 16 + lr;
            int btc = bt < 0 ? 0 : bt;
            int t = btc & (T_LEN - 1);
            const unsigned short* hp = hin + (size_t)btc * 32;
            hc[n] = *(const bf16x8*)(hp + 8 * lg);
            int bts = (t >= d1) ? (btc - d1) : btc;
            bf16x8 v = *(const bf16x8*)(hin + (size_t)bts * 32 + 8 * lg);
            if (t < d1) v = (bf16x8){0, 0, 0, 0, 0, 0, 0, 0};
            hs[n] = v;
#pragma unroll
            for (int m = 0; m < 2; ++m) hcc[n][m] = *(const uint2*)(hp + m * 16 + 4 * lg);
        }

        f32x4 zac[2][2];
#pragma unroll
        for (int m = 0; m < 2; ++m)
#pragma unroll
            for (int n = 0; n < 2; ++n) {
                f32x4 a = __builtin_amdgcn_mfma_f32_16x16x32_bf16(wd0[m], hs[n], (f32x4){0.f, 0.f, 0.f, 0.f}, 0, 0, 0);
                zac[m][n] = __builtin_amdgcn_mfma_f32_16x16x32_bf16(wd1[m], hc[n], a, 0, 0, 0);
            }
#pragma unroll
        for (int m = 0; m < 2; ++m)
#pragma unroll
            for (int n = 0; n < 2; ++n) {
                int rbt = n * 16 + lr;
                uint2 u;
                u.x = pack2(ftanh(zac[m][n][0] + bdv[m].x), ftanh(zac[m][n][1] + bdv[m].y));
                u.y = pack2(ftanh(zac[m][n][2] + bdv[m].z), ftanh(zac[m][n][3] + bdv[m].w));
                *(uint2*)(zp + rbt * 40 + m * 16 + 4 * lg) = u;
            }
        f32x4 racc[2][2];
#pragma unroll
        for (int n = 0; n < 2; ++n) {
            bf16x8 zb = *(const bf16x8*)(zp + (n * 16 + lr) * 40 + 8 * lg);
#pragma unroll
            for (int m = 0; m < 2; ++m)
                racc[m][n] = __builtin_amdgcn_mfma_f32_16x16x32_bf16(wr[m], zb, (f32x4){0.f, 0.f, 0.f, 0.f}, 0, 0, 0);
        }
#pragma unroll
        for (int m = 0; m < 2; ++m)
#pragma unroll
            for (int n = 0; n < 2; ++n) {
                int bt = btb + n * 16 + lr;
                int u_ = bt - (bt0 - H2);
                float h0 = bflo(hcc[n][m].x) + racc[m][n][0] + brv[m].x;
                float h1 = bfhi(hcc[n][m].x) + racc[m][n][1] + brv[m].y;
                float h2 = bflo(hcc[n][m].y) + racc[m][n][2] + brv[m].z;
                float h3 = bfhi(hcc[n][m].y) + racc[m][n][3] + brv[m].w;
                uint2 u;
                u.x = pack2(h0, h1);
                u.y = pack2(h2, h3);
                *(uint2*)(midb + midaddr(u_, m * 32 + lg * 8)) = u;
                if (bt >= bt0)
                    *(uint2*)(hmid + (size_t)bt * 32 + m * 16 + 4 * lg) = u;
            }
    }
    __syncthreads();

#pragma unroll
    for (int m = 0; m < 2; ++m) {
        int ao = (m * 16 + lr) * 32 + 8 * lg;
        wd1[m] = *(const bf16x8*)(W1b + ao);
        wd0[m] = *(const bf16x8*)(W0b + ao);
        wr[m]  = *(const bf16x8*)(Wrb + ao);
        bdv[m] = *(const float4*)(bdb + m * 16 + 4 * lg);
        brv[m] = *(const float4*)(brb + m * 16 + 4 * lg);
    }

    {
        int btb = bt0 + wq * 32;
        bf16x8 hc[2], hs[2];
        uint2 hcc[2][2];
#pragma unroll
        for (int n = 0; n < 2; ++n) {
            int bt = btb + n * 16 + lr;
            int t = bt & (T_LEN - 1);
            int u_ = bt - (bt0 - H2);
            hc[n] = *(const bf16x8*)(midb + midaddr(u_, lg * 16));
            bf16x8 v = *(const bf16x8*)(midb + midaddr(u_ - d2, lg * 16));
            if (t < d2) v = (bf16x8){0, 0, 0, 0, 0, 0, 0, 0};
            hs[n] = v;
#pragma unroll
            for (int m = 0; m < 2; ++m)
                hcc[n][m] = *(const uint2*)(midb + midaddr(u_, m * 32 + lg * 8));
        }

        f32x4 zac[2][2];
#pragma unroll
        for (int m = 0; m < 2; ++m)
#pragma unroll
            for (int n = 0; n < 2; ++n) {
                f32x4 a = __builtin_amdgcn_mfma_f32_16x16x32_bf16(wd0[m], hs[n], (f32x4){0.f, 0.f, 0.f, 0.f}, 0, 0, 0);
                zac[m][n] = __builtin_amdgcn_mfma_f32_16x16x32_bf16(wd1[m], hc[n], a, 0, 0, 0);
            }
#pragma unroll
        for (int m = 0; m < 2; ++m)
#pragma unroll
            for (int n = 0; n < 2; ++n) {
                int rbt = n * 16 + lr;
                uint2 u;
                u.x = pack2(ftanh(zac[m][n][0] + bdv[m].x), ftanh(zac[m][n][1] + bdv[m].y));
                u.y = pack2(ftanh(zac[m][n][2] + bdv[m].z), ftanh(zac[m][n][3] + bdv[m].w));
                *(uint2*)(zp + rbt * 40 + m * 16 + 4 * lg) = u;
            }
        f32x4 racc[2][2];
#pragma unroll
        for (int n = 0; n < 2; ++n) {
            bf16x8 zb = *(const bf16x8*)(zp + (n * 16 + lr) * 40 + 8 * lg);
#pragma unroll
            for (int m = 0; m < 2; ++m)
                racc[m][n] = __builtin_amdgcn_mfma_f32_16x16x32_bf16(wr[m], zb, (f32x4){0.f, 0.f, 0.f, 0.f}, 0, 0, 0);
        }
#pragma unroll
        for (int m = 0; m < 2; ++m)
#pragma unroll
            for (int n = 0; n < 2; ++n) {
                int bt = btb + n * 16 + lr;
                float h0 = bflo(hcc[n][m].x) + racc[m][n][0] + brv[m].x;
                float h1 = bfhi(hcc[n][m].x) + racc[m][n][1] + brv[m].y;
                float h2 = bflo(hcc[n][m].y) + racc[m][n][2] + brv[m].z;
                float h3 = bfhi(hcc[n][m].y) + racc[m][n][3] + brv[m].w;
                uint2 u;
                u.x = pack2(h0, h1);
                u.y = pack2(h2, h3);
                *(uint2*)(hfin + (size_t)bt * 32 + m * 16 + 4 * lg) = u;
            }
    }
}

// ---------- fused skip + final GEMM (R16 verbatim: 124 us measured) ----------
__global__ __launch_bounds__(256, 2) void k_skipfinal(const unsigned short* __restrict__ hist,
                                                      const unsigned short* __restrict__ Wsk2,
                                                      const unsigned short* __restrict__ Wfk,
                                                      const float* __restrict__ bs_sum,
                                                      const float* __restrict__ bfv,
                                                      float* __restrict__ outp) {
    __shared__ char smem[73728];
    const int tid = threadIdx.x;
    const int lane = tid & 63, wq = tid >> 6;
    const int lr = lane & 15, lg = lane >> 4;
    const int wm = wq & 1, wn = wq >> 1;
    const int bt0 = blockIdx.x * BTW;
    const char* histb = (const char*)hist;
    const char* Wsb = (const char*)Wsk2;
    lds_char* smem3 = (lds_char*)smem;

    int asrc[4], bsrc[2];
#pragma unroll
    for (int p = 0; p < 4; ++p) asrc[p] = swz(p * 4096 + tid * 16);
#pragma unroll
    for (int p = 0; p < 2; ++p) bsrc[p] = bt0 * 64 + swz(p * 4096 + tid * 16);

    auto stage = [&](int k) {
        int sl = NL - 1 - k;
        char* base = smem + (k % 3) * RING;
#pragma unroll
        for (int p = 0; p < 4; ++p)
            __builtin_amdgcn_global_load_lds((const glb_u32*)(Wsb + (size_t)sl * 16384 + asrc[p]),
                                             (lds_u32*)(base + p * 4096 + tid * 16), 16, 0, 0);
#pragma unroll
        for (int p = 0; p < 2; ++p)
            __builtin_amdgcn_global_load_lds((const glb_u32*)(histb + (size_t)sl * SLOTB + bsrc[p]),
                                             (lds_u32*)(base + 16384 + p * 4096 + tid * 16), 16, 0, 0);
    };

    f32x4 acc[8][4];
#pragma unroll
    for (int m = 0; m < 8; ++m)
#pragma unroll
        for (int n = 0; n < 4; ++n) acc[m][n] = (f32x4){0.f, 0.f, 0.f, 0.f};

    const int cswz = (lg * 16) ^ (((lr >> 1) & 3) << 4);
    const int arow = wm * 128 + lr;
    const int brow = wn * 64 + lr;

    stage(0);
    stage(1);
    stage(2);

#pragma unroll
    for (int i = 0; i < NL; ++i) {
        if (i >= 1 && i + 2 < NL) stage(i + 2);
        wait_vmcnt(i + 2 < NL ? 12 : (i + 1 < NL ? 6 : 0));
        __builtin_amdgcn_s_barrier();

        lds_char* Ab = smem3 + (i % 3) * RING;
        lds_char* Bb = Ab + 16384;
        bf16x8 af[8], bb[4];
#pragma unroll
        for (int m = 0; m < 8; ++m)
            asm volatile("ds_read_b128 %0, %1" : "=v"(af[m]) : "v"(Ab + (arow + m * 16) * 64 + cswz));
#pragma unroll
        for (int n = 0; n < 4; ++n)
            asm volatile("ds_read_b128 %0, %1" : "=v"(bb[n]) : "v"(Bb + (brow + n * 16) * 64 + cswz));
        asm volatile("s_waitcnt lgkmcnt(0)" ::: "memory");
        __builtin_amdgcn_sched_barrier(0);

#pragma unroll
        for (int m = 0; m < 8; ++m)
#pragma unroll
            for (int n = 0; n < 4; ++n)
                acc[m][n] = __builtin_amdgcn_mfma_f32_16x16x32_bf16(af[m], bb[n], acc[m][n], 0, 0, 0);
        __builtin_amdgcn_s_barrier();
    }
    __syncthreads();

    char* skb = smem;
#pragma unroll
    for (int m = 0; m < 8; ++m) {
        int oc0 = wm * 128 + m * 16 + lg * 4;
        float c0 = bs_sum[oc0], c1 = bs_sum[oc0 + 1], c2 = bs_sum[oc0 + 2], c3 = bs_sum[oc0 + 3];
#pragma unroll
        for (int n = 0; n < 4; ++n) {
            int bt = wn * 64 + n * 16 + lr;
            f32x4 v = acc[m][n];
            uint2 u;
            u.x = pack2(fmaxf(v[0] + c0, 0.f), fmaxf(v[1] + c1, 0.f));
            u.y = pack2(fmaxf(v[2] + c2, 0.f), fmaxf(v[3] + c3, 0.f));
            int L = bt * 512 + oc0 * 2;
            *(uint2*)(skb + (L ^ ((bt & 7) << 4))) = u;
        }
    }
    __syncthreads();

#pragma unroll
    for (int m = 0; m < 8; ++m)
#pragma unroll
        for (int n = 0; n < 4; ++n) acc[m][n] = (f32x4){0.f, 0.f, 0.f, 0.f};

    const unsigned short* Fb = Wfk + (size_t)(wm * 128 + lr) * SC + 8 * lg;

#pragma unroll
    for (int kk = 0; kk < SC / 32; ++kk) {
        bf16x8 fa[8];
#pragma unroll
        for (int m = 0; m < 8; ++m) fa[m] = *(const bf16x8*)(Fb + (size_t)m * 16 * SC + kk * 32);
        bf16x8 sbv[4];
#pragma unroll
        for (int n = 0; n < 4; ++n) {
            int bt = wn * 64 + n * 16 + lr;
            int L = bt * 512 + kk * 64 + lg * 16;
            sbv[n] = *(const bf16x8*)(skb + (L ^ ((bt & 7) << 4)));
        }
#pragma unroll
        for (int m = 0; m < 8; ++m)
#pragma unroll
            for (int n = 0; n < 4; ++n)
                acc[m][n] = __builtin_amdgcn_mfma_f32_16x16x32_bf16(fa[m], sbv[n], acc[m][n], 0, 0, 0);
    }

    int b2 = bt0 >> 15;
    int t0 = bt0 & (T_LEN - 1);
#pragma unroll
    for (int m = 0; m < 8; ++m) {
        int o0 = wm * 128 + m * 16 + lg * 4;
        float q0 = bfv[o0], q1 = bfv[o0 + 1], q2 = bfv[o0 + 2], q3 = bfv[o0 + 3];
#pragma unroll
        for (int n = 0; n < 4; ++n) {
            int t = t0 + wn * 64 + n * 16 + lr;
            f32x4 v = acc[m][n];
            outp[((size_t)(b2 * OUTC + o0 + 0) << 15) + t] = v[0] + q0;
            outp[((size_t)(b2 * OUTC + o0 + 1) << 15) + t] = v[1] + q1;
            outp[((size_t)(b2 * OUTC + o0 + 2) << 15) + t] = v[2] + q2;
            outp[((size_t)(b2 * OUTC + o0 + 3) << 15) + t] = v[3] + q3;
        }
    }
}

extern "C" void kernel_launch(void* const* d_in, const int* in_sizes, int n_in,
                              void* d_out, int out_size, void* d_ws, size_t ws_size,
                              hipStream_t stream) {
    const float* x       = (const float*)d_in[0];
    const float* W_start = (const float*)d_in[1];
    const float* b_start = (const float*)d_in[2];
    const float* Wd      = (const float*)d_in[3];
    const float* bd      = (const float*)d_in[4];
    const float* Wr      = (const float*)d_in[5];
    const float* br      = (const float*)d_in[6];
    const float* Ws      = (const float*)d_in[7];
    const float* bs      = (const float*)d_in[8];
    const float* Wf      = (const float*)d_in[9];
    const float* bfv     = (const float*)d_in[10];

    char* wsb = (char*)d_ws;
    unsigned short* Wsk2 = (unsigned short*)(wsb);                      // 655360 B
    unsigned short* Wfk  = (unsigned short*)(wsb + 655360);             // 131072 B
    unsigned short* Wd1k = (unsigned short*)(wsb + 786432);             // 81920 B
    unsigned short* Wd0k = (unsigned short*)(wsb + 868352);             // 81920 B
    unsigned short* Wrk  = (unsigned short*)(wsb + 950272);             // 81920 B
    float*          bs_sum = (float*)(wsb + 1032192);                   // 1024 B
    char* S1 = wsb + (1 << 20);            // stream slots 1..40 (= hist layers 0..39)
    char* X  = S1 + 40 * SLOTB;            // slot 0

    auto slotptr = [&](int i) -> unsigned short* {
        return (unsigned short*)(i == 0 ? X : S1 + (size_t)(i - 1) * SLOTB);
    };

    k_prep<<<(SC * KTOT + OUTC * SC + 3 * NL * 1024 + SC + 255) / 256, 256, 0, stream>>>(
        Ws, Wf, Wd, Wr, bs, Wsk2, Wfk, Wd1k, Wd0k, Wrk, bs_sum);
    k_start<<<NBT / 256, 256, 0, stream>>>(x, W_start, b_start, slotptr(0));

    for (int g = 0; g < 4; ++g) {
        int base = g * 10;
        for (int j = 0; j < 8; j += 2) {
            int i = base + j;
            k_layer2<<<NBT / 256, 512, 0, stream>>>(
                slotptr(i), slotptr(i + 1), slotptr(i + 2),
                Wd1k + i * 1024, Wd0k + i * 1024, Wrk + i * 1024, bd + i * DC, br + i * RC,
                Wd1k + (i + 1) * 1024, Wd0k + (i + 1) * 1024, Wrk + (i + 1) * 1024,
                bd + (i + 1) * DC, br + (i + 1) * RC,
                1 << j, 1 << (j + 1));
        }
        for (int j = 8; j < 10; ++j) {
            int i = base + j;
            k_layer<<<NBT / 128, 256, 0, stream>>>(slotptr(i), slotptr(i + 1),
                                                   Wd1k + i * 1024, Wd0k + i * 1024, Wrk + i * 1024,
                                                   bd + i * DC, br + i * RC, 1 << j);
        }
    }

    k_skipfinal<<<NBT / BTW, 256, 0, stream>>>((unsigned short*)S1, Wsk2, Wfk, bs_sum, bfv, (float*)d_out);
}

// Round 21
// 415.117 us; speedup vs baseline: 1.1461x; 1.0087x over previous
//
#include <hip/hip_runtime.h>
#include <hip/hip_bf16.h>

#define T_LEN 32768
#define B_N   4
#define RC    32
#define DC    32
#define SC    256
#define OUTC  256
#define NL    40
#define KTOT  (NL * RC)   // 1280
#define NBT   (B_N * T_LEN)
#define SLOTB ((size_t)NBT * 32 * 2)      // 8 MB payload per stream slot
#define SLOTSK (SLOTB + 4864)             // skewed slot stride (breaks HBM channel aliasing)
#define BTW   128                          // bt per k_skipfinal block
#define RING  24576                        // ring slot: A 16 KB + B 8 KB
#define H2    128                          // k_layer2 halo

typedef float f32x4 __attribute__((ext_vector_type(4)));
typedef short bf16x8 __attribute__((ext_vector_type(8)));
typedef __attribute__((address_space(3))) unsigned int lds_u32;
typedef __attribute__((address_space(3))) char lds_char;
typedef __attribute__((address_space(1))) unsigned int glb_u32;

// ---------- helpers ----------
__device__ __forceinline__ unsigned short f2bf_bits(float f) {
    __hip_bfloat16 b = __float2bfloat16(f);
    unsigned short u;
    __builtin_memcpy(&u, &b, 2);
    return u;
}
__device__ __forceinline__ unsigned pack2(float a, float b) {
    return (unsigned)f2bf_bits(a) | ((unsigned)f2bf_bits(b) << 16);
}
__device__ __forceinline__ float bflo(unsigned u) { return __uint_as_float((u & 0xFFFFu) << 16); }
__device__ __forceinline__ float bfhi(unsigned u) { return __uint_as_float(u & 0xFFFF0000u); }
__device__ __forceinline__ float ftanh(float x) {
    float e = __expf(2.f * x);
    return 1.f - 2.f / (e + 1.f);
}
// swizzle involution: XOR col bits 4-5 with (row>>1)&3  (row = byte>>6)
__device__ __forceinline__ int swz(int L) { return L ^ ((((L >> 7) & 3)) << 4); }
// mid-buffer byte address: row u (64 B), col byte c, same involution
__device__ __forceinline__ int midaddr(int u, int c) { return u * 64 + (c ^ (((u >> 1) & 3) << 4)); }
__device__ __forceinline__ void wait_vmcnt(int n) {
    switch (n) {
        case 0: asm volatile("s_waitcnt vmcnt(0)" ::: "memory"); break;
        case 6: asm volatile("s_waitcnt vmcnt(6)" ::: "memory"); break;
        default: asm volatile("s_waitcnt vmcnt(12)" ::: "memory"); break;
    }
}

// ---------- prep: bf16 weight packs + bias sum ----------
__global__ __launch_bounds__(256) void k_prep(const float* __restrict__ Ws,
                                              const float* __restrict__ Wf,
                                              const float* __restrict__ Wd,
                                              const float* __restrict__ Wr,
                                              const float* __restrict__ bs,
                                              unsigned short* __restrict__ Wsk2,
                                              unsigned short* __restrict__ Wfk,
                                              unsigned short* __restrict__ Wd1k,
                                              unsigned short* __restrict__ Wd0k,
                                              unsigned short* __restrict__ Wrk,
                                              float* __restrict__ bs_sum) {
    int g = blockIdx.x * 256 + threadIdx.x;
    if (g < SC * KTOT) {
        int i = g >> 13, r = g & 8191;
        int oc = r >> 5, c = r & 31;
        Wsk2[g] = f2bf_bits(Ws[(i * SC + oc) * RC + c]);
        return;
    }
    g -= SC * KTOT;
    if (g < OUTC * SC) { Wfk[g] = f2bf_bits(Wf[g]); return; }
    g -= OUTC * SC;
    if (g < NL * 1024) {
        int i = g >> 10, r = g & 1023;
        int o = r >> 5, c = r & 31;
        Wd1k[g] = f2bf_bits(Wd[((i * DC + o) * RC + c) * 2 + 1]);
        return;
    }
    g -= NL * 1024;
    if (g < NL * 1024) {
        int i = g >> 10, r = g & 1023;
        int o = r >> 5, c = r & 31;
        Wd0k[g] = f2bf_bits(Wd[((i * DC + o) * RC + c) * 2 + 0]);
        return;
    }
    g -= NL * 1024;
    if (g < NL * 1024) { Wrk[g] = f2bf_bits(Wr[g]); return; }
    g -= NL * 1024;
    if (g < SC) {
        float s = 0.f;
        for (int i = 0; i < NL; ++i) s += bs[i * SC + g];
        bs_sum[g] = s;
    }
}

// ---------- start conv -> bf16 stream slot 0 ----------
__global__ __launch_bounds__(256) void k_start(const float* __restrict__ x,
                                               const float* __restrict__ Wst,
                                               const float* __restrict__ bst,
                                               unsigned short* __restrict__ h0) {
    int g = blockIdx.x * 256 + threadIdx.x;
    float xv = x[g];
    unsigned u[16];
#pragma unroll
    for (int q = 0; q < 16; ++q) {
        float a = Wst[2 * q] * xv + bst[2 * q];
        float b = Wst[2 * q + 1] * xv + bst[2 * q + 1];
        u[q] = pack2(a, b);
    }
    unsigned short* op = h0 + (size_t)g * 32;
#pragma unroll
    for (int q = 0; q < 4; ++q) *(uint4*)&op[q * 8] = *(uint4*)&u[q * 4];
}

// ---------- one WaveNet layer: MFMA, bf16 stream (R8 verbatim; used for d=256,512) ----------
__global__ __launch_bounds__(256, 4) void k_layer(const unsigned short* __restrict__ hprev,
                                                  unsigned short* __restrict__ hnext,
                                                  const unsigned short* __restrict__ Wd1k,
                                                  const unsigned short* __restrict__ Wd0k,
                                                  const unsigned short* __restrict__ Wrk,
                                                  const float* __restrict__ bd,
                                                  const float* __restrict__ br,
                                                  int d) {
    __shared__ unsigned short zbuf[4][32 * 40];
    int lane = threadIdx.x & 63;
    int wq = threadIdx.x >> 6;
    int lr = lane & 15, lg = lane >> 4;
    int btb = blockIdx.x * 128 + wq * 32;
    unsigned short* zp = &zbuf[wq][0];

    bf16x8 wd1[2], wd0[2], wr[2];
#pragma unroll
    for (int m = 0; m < 2; ++m) {
        int ao = (m * 16 + lr) * 32 + 8 * lg;
        wd1[m] = *(const bf16x8*)(Wd1k + ao);
        wd0[m] = *(const bf16x8*)(Wd0k + ao);
        wr[m]  = *(const bf16x8*)(Wrk + ao);
    }

    bf16x8 hc[2], hs[2];
    uint2 hcc[2][2];
#pragma unroll
    for (int n = 0; n < 2; ++n) {
        int bt = btb + n * 16 + lr;
        int t = bt & (T_LEN - 1);
        const unsigned short* hp = hprev + (size_t)bt * 32;
        hc[n] = *(const bf16x8*)(hp + 8 * lg);
        int bts = (t >= d) ? (bt - d) : bt;
        bf16x8 v = *(const bf16x8*)(hprev + (size_t)bts * 32 + 8 * lg);
        if (t < d) v = (bf16x8){0, 0, 0, 0, 0, 0, 0, 0};
        hs[n] = v;
#pragma unroll
        for (int m = 0; m < 2; ++m) hcc[n][m] = *(const uint2*)(hp + m * 16 + 4 * lg);
    }

    f32x4 zac[2][2];
#pragma unroll
    for (int m = 0; m < 2; ++m)
#pragma unroll
        for (int n = 0; n < 2; ++n) {
            f32x4 a = __builtin_amdgcn_mfma_f32_16x16x32_bf16(wd0[m], hs[n], (f32x4){0.f, 0.f, 0.f, 0.f}, 0, 0, 0);
            zac[m][n] = __builtin_amdgcn_mfma_f32_16x16x32_bf16(wd1[m], hc[n], a, 0, 0, 0);
        }

#pragma unroll
    for (int m = 0; m < 2; ++m) {
        float4 bdv = *(const float4*)(bd + m * 16 + 4 * lg);
#pragma unroll
        for (int n = 0; n < 2; ++n) {
            int rbt = n * 16 + lr;
            float z0 = ftanh(zac[m][n][0] + bdv.x);
            float z1 = ftanh(zac[m][n][1] + bdv.y);
            float z2 = ftanh(zac[m][n][2] + bdv.z);
            float z3 = ftanh(zac[m][n][3] + bdv.w);
            uint2 u;
            u.x = pack2(z0, z1);
            u.y = pack2(z2, z3);
            *(uint2*)(zp + rbt * 40 + m * 16 + 4 * lg) = u;
        }
    }

    f32x4 racc[2][2];
#pragma unroll
    for (int n = 0; n < 2; ++n) {
        int rbt = n * 16 + lr;
        bf16x8 zb = *(const bf16x8*)(zp + rbt * 40 + 8 * lg);
#pragma unroll
        for (int m = 0; m < 2; ++m)
            racc[m][n] = __builtin_amdgcn_mfma_f32_16x16x32_bf16(wr[m], zb, (f32x4){0.f, 0.f, 0.f, 0.f}, 0, 0, 0);
    }

#pragma unroll
    for (int m = 0; m < 2; ++m) {
        float4 brv = *(const float4*)(br + m * 16 + 4 * lg);
#pragma unroll
        for (int n = 0; n < 2; ++n) {
            int bt = btb + n * 16 + lr;
            float h0 = bflo(hcc[n][m].x) + racc[m][n][0] + brv.x;
            float h1 = bfhi(hcc[n][m].x) + racc[m][n][1] + brv.y;
            float h2 = bflo(hcc[n][m].y) + racc[m][n][2] + brv.z;
            float h3 = bfhi(hcc[n][m].y) + racc[m][n][3] + brv.w;
            uint2 u;
            u.x = pack2(h0, h1);
            u.y = pack2(h2, h3);
            *(uint2*)(hnext + (size_t)bt * 32 + m * 16 + 4 * lg) = u;
        }
    }
}

// ---------- fused pair of layers (d2 = 2*d1 <= 128) — R18 verbatim ----------
__global__ __launch_bounds__(512, 2) void k_layer2(const unsigned short* __restrict__ hin,
                                                   unsigned short* __restrict__ hmid,
                                                   unsigned short* __restrict__ hfin,
                                                   const unsigned short* __restrict__ W1a,
                                                   const unsigned short* __restrict__ W0a,
                                                   const unsigned short* __restrict__ Wra,
                                                   const float* __restrict__ bda,
                                                   const float* __restrict__ bra,
                                                   const unsigned short* __restrict__ W1b,
                                                   const unsigned short* __restrict__ W0b,
                                                   const unsigned short* __restrict__ Wrb,
                                                   const float* __restrict__ bdb,
                                                   const float* __restrict__ brb,
                                                   int d1, int d2) {
    __shared__ char midb[384 * 64];                 // 24 KB mid buffer
    __shared__ unsigned short zbuf[8][32 * 40];     // 20 KB
    const int tid = threadIdx.x;
    const int lane = tid & 63, wq = tid >> 6;
    const int lr = lane & 15, lg = lane >> 4;
    const int bt0 = blockIdx.x * 256;
    unsigned short* zp = &zbuf[wq][0];

    bf16x8 wd1[2], wd0[2], wr[2];
    float4 bdv[2], brv[2];
#pragma unroll
    for (int m = 0; m < 2; ++m) {
        int ao = (m * 16 + lr) * 32 + 8 * lg;
        wd1[m] = *(const bf16x8*)(W1a + ao);
        wd0[m] = *(const bf16x8*)(W0a + ao);
        wr[m]  = *(const bf16x8*)(Wra + ao);
        bdv[m] = *(const float4*)(bda + m * 16 + 4 * lg);
        brv[m] = *(const float4*)(bra + m * 16 + 4 * lg);
    }

#pragma unroll 1
    for (int pass = 0; pass < 2; ++pass) {
        int tl = (pass == 0) ? wq : (wq + 8);
        if (pass == 1 && wq >= 4) break;
        int btb = bt0 - H2 + tl * 32;

        bf16x8 hc[2], hs[2];
        uint2 hcc[2][2];
#pragma unroll
        for (int n = 0; n < 2; ++n) {
            int bt = btb + n * 16 + lr;
            int btc = bt < 0 ? 0 : bt;
            int t = btc & (T_LEN - 1);
            const unsigned short* hp = hin + (size_t)btc * 32;
            hc[n] = *(const bf16x8*)(hp + 8 * lg);
            int bts = (t >= d1) ? (btc - d1) : btc;
            bf16x8 v = *(const bf16x8*)(hin + (size_t)bts * 32 + 8 * lg);
            if (t < d1) v = (bf16x8){0, 0, 0, 0, 0, 0, 0, 0};
            hs[n] = v;
#pragma unroll
            for (int m = 0; m < 2; ++m) hcc[n][m] = *(const uint2*)(hp + m * 16 + 4 * lg);
        }

        f32x4 zac[2][2];
#pragma unroll
        for (int m = 0; m < 2; ++m)
#pragma unroll
            for (int n = 0; n < 2; ++n) {
                f32x4 a = __builtin_amdgcn_mfma_f32_16x16x32_bf16(wd0[m], hs[n], (f32x4){0.f, 0.f, 0.f, 0.f}, 0, 0, 0);
                zac[m][n] = __builtin_amdgcn_mfma_f32_16x16x32_bf16(wd1[m], hc[n], a, 0, 0, 0);
            }
#pragma unroll
        for (int m = 0; m < 2; ++m)
#pragma unroll
            for (int n = 0; n < 2; ++n) {
                int rbt = n * 16 + lr;
                uint2 u;
                u.x = pack2(ftanh(zac[m][n][0] + bdv[m].x), ftanh(zac[m][n][1] + bdv[m].y));
                u.y = pack2(ftanh(zac[m][n][2] + bdv[m].z), ftanh(zac[m][n][3] + bdv[m].w));
                *(uint2*)(zp + rbt * 40 + m * 16 + 4 * lg) = u;
            }
        f32x4 racc[2][2];
#pragma unroll
        for (int n = 0; n < 2; ++n) {
            bf16x8 zb = *(const bf16x8*)(zp + (n * 16 + lr) * 40 + 8 * lg);
#pragma unroll
            for (int m = 0; m < 2; ++m)
                racc[m][n] = __builtin_amdgcn_mfma_f32_16x16x32_bf16(wr[m], zb, (f32x4){0.f, 0.f, 0.f, 0.f}, 0, 0, 0);
        }
#pragma unroll
        for (int m = 0; m < 2; ++m)
#pragma unroll
            for (int n = 0; n < 2; ++n) {
                int bt = btb + n * 16 + lr;
                int u_ = bt - (bt0 - H2);
                float h0 = bflo(hcc[n][m].x) + racc[m][n][0] + brv[m].x;
                float h1 = bfhi(hcc[n][m].x) + racc[m][n][1] + brv[m].y;
                float h2 = bflo(hcc[n][m].y) + racc[m][n][2] + brv[m].z;
                float h3 = bfhi(hcc[n][m].y) + racc[m][n][3] + brv[m].w;
                uint2 u;
                u.x = pack2(h0, h1);
                u.y = pack2(h2, h3);
                *(uint2*)(midb + midaddr(u_, m * 32 + lg * 8)) = u;
                if (bt >= bt0)
                    *(uint2*)(hmid + (size_t)bt * 32 + m * 16 + 4 * lg) = u;
            }
    }
    __syncthreads();

#pragma unroll
    for (int m = 0; m < 2; ++m) {
        int ao = (m * 16 + lr) * 32 + 8 * lg;
        wd1[m] = *(const bf16x8*)(W1b + ao);
        wd0[m] = *(const bf16x8*)(W0b + ao);
        wr[m]  = *(const bf16x8*)(Wrb + ao);
        bdv[m] = *(const float4*)(bdb + m * 16 + 4 * lg);
        brv[m] = *(const float4*)(brb + m * 16 + 4 * lg);
    }

    {
        int btb = bt0 + wq * 32;
        bf16x8 hc[2], hs[2];
        uint2 hcc[2][2];
#pragma unroll
        for (int n = 0; n < 2; ++n) {
            int bt = btb + n * 16 + lr;
            int t = bt & (T_LEN - 1);
            int u_ = bt - (bt0 - H2);
            hc[n] = *(const bf16x8*)(midb + midaddr(u_, lg * 16));
            bf16x8 v = *(const bf16x8*)(midb + midaddr(u_ - d2, lg * 16));
            if (t < d2) v = (bf16x8){0, 0, 0, 0, 0, 0, 0, 0};
            hs[n] = v;
#pragma unroll
            for (int m = 0; m < 2; ++m)
                hcc[n][m] = *(const uint2*)(midb + midaddr(u_, m * 32 + lg * 8));
        }

        f32x4 zac[2][2];
#pragma unroll
        for (int m = 0; m < 2; ++m)
#pragma unroll
            for (int n = 0; n < 2; ++n) {
                f32x4 a = __builtin_amdgcn_mfma_f32_16x16x32_bf16(wd0[m], hs[n], (f32x4){0.f, 0.f, 0.f, 0.f}, 0, 0, 0);
                zac[m][n] = __builtin_amdgcn_mfma_f32_16x16x32_bf16(wd1[m], hc[n], a, 0, 0, 0);
            }
#pragma unroll
        for (int m = 0; m < 2; ++m)
#pragma unroll
            for (int n = 0; n < 2; ++n) {
                int rbt = n * 16 + lr;
                uint2 u;
                u.x = pack2(ftanh(zac[m][n][0] + bdv[m].x), ftanh(zac[m][n][1] + bdv[m].y));
                u.y = pack2(ftanh(zac[m][n][2] + bdv[m].z), ftanh(zac[m][n][3] + bdv[m].w));
                *(uint2*)(zp + rbt * 40 + m * 16 + 4 * lg) = u;
            }
        f32x4 racc[2][2];
#pragma unroll
        for (int n = 0; n < 2; ++n) {
            bf16x8 zb = *(const bf16x8*)(zp + (n * 16 + lr) * 40 + 8 * lg);
#pragma unroll
            for (int m = 0; m < 2; ++m)
                racc[m][n] = __builtin_amdgcn_mfma_f32_16x16x32_bf16(wr[m], zb, (f32x4){0.f, 0.f, 0.f, 0.f}, 0, 0, 0);
        }
#pragma unroll
        for (int m = 0; m < 2; ++m)
#pragma unroll
            for (int n = 0; n < 2; ++n) {
                int bt = btb + n * 16 + lr;
                float h0 = bflo(hcc[n][m].x) + racc[m][n][0] + brv[m].x;
                float h1 = bfhi(hcc[n][m].x) + racc[m][n][1] + brv[m].y;
                float h2 = bflo(hcc[n][m].y) + racc[m][n][2] + brv[m].z;
                float h3 = bfhi(hcc[n][m].y) + racc[m][n][3] + brv[m].w;
                uint2 u;
                u.x = pack2(h0, h1);
                u.y = pack2(h2, h3);
                *(uint2*)(hfin + (size_t)bt * 32 + m * 16 + 4 * lg) = u;
            }
    }
}

// ---------- fused skip + final GEMM (R16 structure; skewed slot stride) ----------
__global__ __launch_bounds__(256, 2) void k_skipfinal(const unsigned short* __restrict__ hist,
                                                      const unsigned short* __restrict__ Wsk2,
                                                      const unsigned short* __restrict__ Wfk,
                                                      const float* __restrict__ bs_sum,
                                                      const float* __restrict__ bfv,
                                                      float* __restrict__ outp) {
    __shared__ char smem[73728];
    const int tid = threadIdx.x;
    const int lane = tid & 63, wq = tid >> 6;
    const int lr = lane & 15, lg = lane >> 4;
    const int wm = wq & 1, wn = wq >> 1;
    const int bt0 = blockIdx.x * BTW;
    const char* histb = (const char*)hist;
    const char* Wsb = (const char*)Wsk2;
    lds_char* smem3 = (lds_char*)smem;

    int asrc[4], bsrc[2];
#pragma unroll
    for (int p = 0; p < 4; ++p) asrc[p] = swz(p * 4096 + tid * 16);
#pragma unroll
    for (int p = 0; p < 2; ++p) bsrc[p] = bt0 * 64 + swz(p * 4096 + tid * 16);

    auto stage = [&](int k) {
        int sl = NL - 1 - k;
        char* base = smem + (k % 3) * RING;
#pragma unroll
        for (int p = 0; p < 4; ++p)
            __builtin_amdgcn_global_load_lds((const glb_u32*)(Wsb + (size_t)sl * 16384 + asrc[p]),
                                             (lds_u32*)(base + p * 4096 + tid * 16), 16, 0, 0);
#pragma unroll
        for (int p = 0; p < 2; ++p)
            __builtin_amdgcn_global_load_lds((const glb_u32*)(histb + (size_t)sl * SLOTSK + bsrc[p]),
                                             (lds_u32*)(base + 16384 + p * 4096 + tid * 16), 16, 0, 0);
    };

    f32x4 acc[8][4];
#pragma unroll
    for (int m = 0; m < 8; ++m)
#pragma unroll
        for (int n = 0; n < 4; ++n) acc[m][n] = (f32x4){0.f, 0.f, 0.f, 0.f};

    const int cswz = (lg * 16) ^ (((lr >> 1) & 3) << 4);
    const int arow = wm * 128 + lr;
    const int brow = wn * 64 + lr;

    stage(0);
    stage(1);
    stage(2);

#pragma unroll
    for (int i = 0; i < NL; ++i) {
        if (i >= 1 && i + 2 < NL) stage(i + 2);
        wait_vmcnt(i + 2 < NL ? 12 : (i + 1 < NL ? 6 : 0));
        __builtin_amdgcn_s_barrier();

        lds_char* Ab = smem3 + (i % 3) * RING;
        lds_char* Bb = Ab + 16384;
        bf16x8 af[8], bb[4];
#pragma unroll
        for (int m = 0; m < 8; ++m)
            asm volatile("ds_read_b128 %0, %1" : "=v"(af[m]) : "v"(Ab + (arow + m * 16) * 64 + cswz));
#pragma unroll
        for (int n = 0; n < 4; ++n)
            asm volatile("ds_read_b128 %0, %1" : "=v"(bb[n]) : "v"(Bb + (brow + n * 16) * 64 + cswz));
        asm volatile("s_waitcnt lgkmcnt(0)" ::: "memory");
        __builtin_amdgcn_sched_barrier(0);

#pragma unroll
        for (int m = 0; m < 8; ++m)
#pragma unroll
            for (int n = 0; n < 4; ++n)
                acc[m][n] = __builtin_amdgcn_mfma_f32_16x16x32_bf16(af[m], bb[n], acc[m][n], 0, 0, 0);
        __builtin_amdgcn_s_barrier();
    }
    __syncthreads();

    char* skb = smem;
#pragma unroll
    for (int m = 0; m < 8; ++m) {
        int oc0 = wm * 128 + m * 16 + lg * 4;
        float c0 = bs_sum[oc0], c1 = bs_sum[oc0 + 1], c2 = bs_sum[oc0 + 2], c3 = bs_sum[oc0 + 3];
#pragma unroll
        for (int n = 0; n < 4; ++n) {
            int bt = wn * 64 + n * 16 + lr;
            f32x4 v = acc[m][n];
            uint2 u;
            u.x = pack2(fmaxf(v[0] + c0, 0.f), fmaxf(v[1] + c1, 0.f));
            u.y = pack2(fmaxf(v[2] + c2, 0.f), fmaxf(v[3] + c3, 0.f));
            int L = bt * 512 + oc0 * 2;
            *(uint2*)(skb + (L ^ ((bt & 7) << 4))) = u;
        }
    }
    __syncthreads();

#pragma unroll
    for (int m = 0; m < 8; ++m)
#pragma unroll
        for (int n = 0; n < 4; ++n) acc[m][n] = (f32x4){0.f, 0.f, 0.f, 0.f};

    const unsigned short* Fb = Wfk + (size_t)(wm * 128 + lr) * SC + 8 * lg;

#pragma unroll
    for (int kk = 0; kk < SC / 32; ++kk) {
        bf16x8 fa[8];
#pragma unroll
        for (int m = 0; m < 8; ++m) fa[m] = *(const bf16x8*)(Fb + (size_t)m * 16 * SC + kk * 32);
        bf16x8 sbv[4];
#pragma unroll
        for (int n = 0; n < 4; ++n) {
            int bt = wn * 64 + n * 16 + lr;
            int L = bt * 512 + kk * 64 + lg * 16;
            sbv[n] = *(const bf16x8*)(skb + (L ^ ((bt & 7) << 4)));
        }
#pragma unroll
        for (int m = 0; m < 8; ++m)
#pragma unroll
            for (int n = 0; n < 4; ++n)
                acc[m][n] = __builtin_amdgcn_mfma_f32_16x16x32_bf16(fa[m], sbv[n], acc[m][n], 0, 0, 0);
    }

    int b2 = bt0 >> 15;
    int t0 = bt0 & (T_LEN - 1);
#pragma unroll
    for (int m = 0; m < 8; ++m) {
        int o0 = wm * 128 + m * 16 + lg * 4;
        float q0 = bfv[o0], q1 = bfv[o0 + 1], q2 = bfv[o0 + 2], q3 = bfv[o0 + 3];
#pragma unroll
        for (int n = 0; n < 4; ++n) {
            int t = t0 + wn * 64 + n * 16 + lr;
            f32x4 v = acc[m][n];
            outp[((size_t)(b2 * OUTC + o0 + 0) << 15) + t] = v[0] + q0;
            outp[((size_t)(b2 * OUTC + o0 + 1) << 15) + t] = v[1] + q1;
            outp[((size_t)(b2 * OUTC + o0 + 2) << 15) + t] = v[2] + q2;
            outp[((size_t)(b2 * OUTC + o0 + 3) << 15) + t] = v[3] + q3;
        }
    }
}

extern "C" void kernel_launch(void* const* d_in, const int* in_sizes, int n_in,
                              void* d_out, int out_size, void* d_ws, size_t ws_size,
                              hipStream_t stream) {
    const float* x       = (const float*)d_in[0];
    const float* W_start = (const float*)d_in[1];
    const float* b_start = (const float*)d_in[2];
    const float* Wd      = (const float*)d_in[3];
    const float* bd      = (const float*)d_in[4];
    const float* Wr      = (const float*)d_in[5];
    const float* br      = (const float*)d_in[6];
    const float* Ws      = (const float*)d_in[7];
    const float* bs      = (const float*)d_in[8];
    const float* Wf      = (const float*)d_in[9];
    const float* bfv     = (const float*)d_in[10];

    char* wsb = (char*)d_ws;
    unsigned short* Wsk2 = (unsigned short*)(wsb);                      // 655360 B
    unsigned short* Wfk  = (unsigned short*)(wsb + 655360);             // 131072 B
    unsigned short* Wd1k = (unsigned short*)(wsb + 786432);             // 81920 B
    unsigned short* Wd0k = (unsigned short*)(wsb + 868352);             // 81920 B
    unsigned short* Wrk  = (unsigned short*)(wsb + 950272);             // 81920 B
    float*          bs_sum = (float*)(wsb + 1032192);                   // 1024 B
    char* SLOTS = wsb + (1 << 20);   // stream slots 0..40 at skewed stride (payload 8 MB + 4864 skew)

    auto slotptr = [&](int i) -> unsigned short* {
        return (unsigned short*)(SLOTS + (size_t)i * SLOTSK);
    };

    k_prep<<<(SC * KTOT + OUTC * SC + 3 * NL * 1024 + SC + 255) / 256, 256, 0, stream>>>(
        Ws, Wf, Wd, Wr, bs, Wsk2, Wfk, Wd1k, Wd0k, Wrk, bs_sum);
    k_start<<<NBT / 256, 256, 0, stream>>>(x, W_start, b_start, slotptr(0));

    for (int g = 0; g < 4; ++g) {
        int base = g * 10;
        for (int j = 0; j < 8; j += 2) {
            int i = base + j;
            k_layer2<<<NBT / 256, 512, 0, stream>>>(
                slotptr(i), slotptr(i + 1), slotptr(i + 2),
                Wd1k + i * 1024, Wd0k + i * 1024, Wrk + i * 1024, bd + i * DC, br + i * RC,
                Wd1k + (i + 1) * 1024, Wd0k + (i + 1) * 1024, Wrk + (i + 1) * 1024,
                bd + (i + 1) * DC, br + (i + 1) * RC,
                1 << j, 1 << (j + 1));
        }
        for (int j = 8; j < 10; ++j) {
            int i = base + j;
            k_layer<<<NBT / 128, 256, 0, stream>>>(slotptr(i), slotptr(i + 1),
                                                   Wd1k + i * 1024, Wd0k + i * 1024, Wrk + i * 1024,
                                                   bd + i * DC, br + i * RC, 1 << j);
        }
    }

    // hist for skipfinal = stream slots 1..40 (= layer outputs), at skewed stride
    k_skipfinal<<<NBT / BTW, 256, 0, stream>>>(slotptr(1), Wsk2, Wfk, bs_sum, bfv, (float*)d_out);
}